// Round 4
// baseline (188664.709 us; speedup 1.0000x reference)
//
#include <hip/hip_runtime.h>

typedef _Float16 f16;
typedef _Float16 f16x8 __attribute__((ext_vector_type(8)));
typedef float f32x4 __attribute__((ext_vector_type(4)));

#define BS 64
#define SL 256
#define FL 256
#define SI 512
#define SH 512
#define NBLK 128
#define ESTEPS 1027            // 1024 + 3 wavefront diagonals
#define DSTEPS 4096
#define NSTEP (ESTEPS + DSTEPS)

__device__ __forceinline__ float sigmoidf_(float x) { return 1.f / (1.f + __expf(-x)); }
__device__ __forceinline__ float tanhf_(float x) { float e = __expf(2.f * x); return 1.f - 2.f / (e + 1.f); }

// Weights packed in MFMA-fragment order (unchanged from Round 2):
// widx = (((((cell*32+nt)*4+g)*2+kh)*16+kk)*64 + lane)*8 + j
// n = g*512 + nt*16 + (lane&15), k = kh*512 + kk*32 + (lane>>4)*8 + j
__global__ void conv_w(const float* __restrict__ W, const float* __restrict__ V,
                       f16* __restrict__ out) {
  long idx = (long)blockIdx.x * blockDim.x + threadIdx.x;  // total 2^25
  int j    = (int)(idx & 7);
  int lane = (int)((idx >> 3) & 63);
  int kk   = (int)((idx >> 9) & 15);
  int kh   = (int)((idx >> 13) & 1);
  int g    = (int)((idx >> 14) & 3);
  int nt   = (int)((idx >> 16) & 31);
  long cell = idx >> 21;
  int n = g * 512 + nt * 16 + (lane & 15);
  int k = kh * 512 + kk * 32 + (lane >> 4) * 8 + j;
  float v = (k < 512) ? W[(cell * 512 + k) * 2048 + n]
                      : V[(cell * 512 + (k - 512)) * 2048 + n];
  out[idx] = (f16)v;
}

__global__ void conv_x(const float* __restrict__ x, f16* __restrict__ xt) {
  long idx = (long)blockIdx.x * blockDim.x + threadIdx.x;  // 256*64*512
  int i = (int)(idx & 511);
  int b = (int)((idx >> 9) & 63);
  int t = (int)(idx >> 15);
  xt[idx] = (f16)x[((long)b * SL + t) * SI + i];
}

__global__ void conv_fin(const float* __restrict__ finW, f16* __restrict__ fint) {
  long idx = (long)blockIdx.x * blockDim.x + threadIdx.x;  // 512*512
  int k = (int)(idx & 511);
  int n = (int)(idx >> 9);
  fint[idx] = (f16)finW[(long)k * SI + n];
}

// h_enc both parities = enc_h0 ; h_dec parity-1 slabs = dec_h0
__global__ void init_state(const float* __restrict__ h0e, const float* __restrict__ h0d,
                           f16* __restrict__ h_enc, f16* __restrict__ h_dec) {
  long idx = (long)blockIdx.x * blockDim.x + threadIdx.x;  // 4*64*512 = 131072
  f16 he = (f16)h0e[idx];
  h_enc[idx] = he;
  h_enc[idx + 131072] = he;
  h_dec[idx + 131072] = (f16)h0d[idx];
}

// Persistent kernel. 128 blocks x 512 threads. Block = (e-slot, nt).
// Encoder: anti-diagonal wavefront, slot e computes cell (v=d-e, e). 1027 steps.
// Decoder: slot e active when (dd&3)==e. 4096 steps.
// Weights: single register buffer B[16] (64 VGPR), prefetched post-MFMA.
// c state: 2 fp32 registers per thread, never leaves the block.
__global__ __launch_bounds__(512, 2) void lstm_persist(
    const f16* __restrict__ xt,
    const f16* __restrict__ wt_enc, const f16* __restrict__ wt_dec,
    const float* __restrict__ enc_b, const float* __restrict__ dec_b,
    const float* __restrict__ enc_c0, const float* __restrict__ dec_c0,
    f16* __restrict__ h_enc, f16* __restrict__ h_dec,
    f16* __restrict__ ys, int* __restrict__ ctr) {
  const int tid = threadIdx.x;
  const int lane = tid & 63;
  const int wid = tid >> 6;     // 0..7
  const int g = wid & 3;        // gate
  const int kh = wid >> 2;      // K-half
  const int col = lane & 15;
  const int kg = lane >> 4;
  const int eslot = blockIdx.x >> 5;
  const int nt = blockIdx.x & 31;
  const int n0 = nt << 4;

  __shared__ float zred[8][64][17];

  const long wslice = ((long)(nt * 4 + g) * 2 + kh) * 8192 + lane * 8;
  const long wcs = (long)1 << 21;  // elements per cell slab
  const int HSz = BS * SH;

  f16x8 B[16];
  {  // preload first active cell: encoder (v=0, e=eslot) -> cell L=0,e=eslot
    const f16* w = wt_enc + (long)eslot * wcs + wslice;
#pragma unroll
    for (int kk = 0; kk < 16; ++kk) B[kk] = *(const f16x8*)(w + kk * 512);
  }

  float c0 = 0.f, c1 = 0.f;          // c registers
  const int grow = (tid >> 4) * 2;   // gate-phase base row
  const int gci = tid & 15;

  for (int s = 0; s < NSTEP; ++s) {
    bool active;
    const f16 *inp = nullptr, *hin = nullptr;
    f16* hout = nullptr;
    const float* bias = nullptr;
    const float* c0src = nullptr;
    const f16* wnext = nullptr;
    int ysj = -1;

    if (s < ESTEPS) {
      const int d = s, v = d - eslot, p = d & 1;
      active = (v >= 0) && (v < 1024);
      if (active) {
        const int L = v & 3, t = v >> 2;
        inp = (eslot == 0) ? (xt + (long)t * HSz)
                           : (h_enc + (p * 4 + (eslot - 1)) * HSz);
        hin  = h_enc + (p * 4 + eslot) * HSz;
        hout = h_enc + ((1 - p) * 4 + eslot) * HSz;
        bias = enc_b + (L * 4 + eslot) * 2048;
        if (v == 0) c0src = enc_c0 + eslot * HSz;
        wnext = (v + 1 < 1024)
                    ? wt_enc + (long)(((v + 1) & 3) * 4 + eslot) * wcs + wslice
                    : wt_dec + (long)eslot * wcs + wslice;  // dec (v=0,eslot)
      }
    } else {
      const int dd = s - ESTEPS, v = dd >> 2, e = dd & 3, par = v & 1;
      active = (e == eslot);
      if (active) {
        const int L = v & 3;
        if (e == 0)
          inp = (v == 0) ? (h_enc + (1 * 4 + 3) * HSz)            // state0
                         : (h_dec + ((par ^ 1) * 4 + 3) * HSz);   // (v-1,3)
        else
          inp = h_dec + (par * 4 + (e - 1)) * HSz;                // (v,e-1)
        hin  = h_dec + ((par ^ 1) * 4 + e) * HSz;                 // (v-1,e)
        hout = h_dec + (par * 4 + e) * HSz;
        bias = dec_b + (L * 4 + e) * 2048;
        if (v == 0) c0src = dec_c0 + e * HSz;
        if (e == 3) ysj = v;
        if (v + 1 < 1024)
          wnext = wt_dec + (long)(((v + 1) & 3) * 4 + eslot) * wcs + wslice;
      }
    }

    if (active) {
      // ---- MFMA phase: z partials for this wave's (gate, K-half) ----
      const f16* abase = ((kh == 0) ? inp : hin) + col * SH + kg * 8;
      f32x4 acc[4];
#pragma unroll
      for (int mi = 0; mi < 4; ++mi) acc[mi] = 0.f;

#pragma unroll
      for (int kk = 0; kk < 16; ++kk) {
        const f16* ab = abase + kk * 32;
        f16x8 a0 = *(const f16x8*)(ab + (0 * 16) * SH);
        f16x8 a1 = *(const f16x8*)(ab + (1 * 16) * SH);
        f16x8 a2 = *(const f16x8*)(ab + (2 * 16) * SH);
        f16x8 a3 = *(const f16x8*)(ab + (3 * 16) * SH);
        acc[0] = __builtin_amdgcn_mfma_f32_16x16x32_f16(a0, B[kk], acc[0], 0, 0, 0);
        acc[1] = __builtin_amdgcn_mfma_f32_16x16x32_f16(a1, B[kk], acc[1], 0, 0, 0);
        acc[2] = __builtin_amdgcn_mfma_f32_16x16x32_f16(a2, B[kk], acc[2], 0, 0, 0);
        acc[3] = __builtin_amdgcn_mfma_f32_16x16x32_f16(a3, B[kk], acc[3], 0, 0, 0);
      }

      // ---- prefetch next active cell's weights into the SAME buffer ----
      if (wnext) {
#pragma unroll
        for (int kk = 0; kk < 16; ++kk) B[kk] = *(const f16x8*)(wnext + kk * 512);
      }

      // ---- cross-wave K reduction via LDS ----
#pragma unroll
      for (int mi = 0; mi < 4; ++mi)
#pragma unroll
        for (int r = 0; r < 4; ++r)
          zred[wid][mi * 16 + kg * 4 + r][col] = acc[mi][r];

      __syncthreads();

      // ---- gate phase: 2 rows per thread, c in registers ----
      {
        const int n = n0 + gci;
        const float bf = bias[n], bi = bias[512 + n],
                    bg = bias[1024 + n], bo = bias[1536 + n];
#pragma unroll
        for (int rr = 0; rr < 2; ++rr) {
          const int row = grow + rr;
          float zf = bf + zred[0][row][gci] + zred[4][row][gci];
          float zi = bi + zred[1][row][gci] + zred[5][row][gci];
          float zg = bg + zred[2][row][gci] + zred[6][row][gci];
          float zo = bo + zred[3][row][gci] + zred[7][row][gci];
          float f = sigmoidf_(zf);
          float i = sigmoidf_(zi);
          float gg = tanhf_(zg);
          float o = sigmoidf_(zo);
          float cin = c0src ? c0src[row * SH + n] : (rr == 0 ? c0 : c1);
          float cc = f * cin + i * gg;
          if (rr == 0) c0 = cc; else c1 = cc;
          f16 h = (f16)(o * tanhf_(cc));
          hout[row * SH + n] = h;
          if (ysj >= 0) ys[((long)row * 1024 + ysj) * SH + n] = h;
        }
      }
    }

    // ---- device-wide barrier ----
    __syncthreads();  // drain all waves' stores (vmcnt) before leader signals
    if (tid == 0) {
      __threadfence();
      __hip_atomic_fetch_add(ctr, 1, __ATOMIC_RELEASE, __HIP_MEMORY_SCOPE_AGENT);
      const int target = (s + 1) * NBLK;
      while (__hip_atomic_load(ctr, __ATOMIC_ACQUIRE, __HIP_MEMORY_SCOPE_AGENT) < target)
        __builtin_amdgcn_s_sleep(2);
    }
    __syncthreads();
  }
}

// out[m][n] = sigmoid( ys[m][:] @ fint[n][:] + fin_b[n] )
__global__ __launch_bounds__(256) void final_gemm(const f16* __restrict__ ys,
                                                  const f16* __restrict__ fint,
                                                  const float* __restrict__ finb,
                                                  float* __restrict__ out) {
  const int lane = threadIdx.x & 63;
  const int w = threadIdx.x >> 6;
  const int col = lane & 15;
  const int kg = lane >> 4;
  const long m0 = (long)blockIdx.y * 64;
  const int n0 = (blockIdx.x * 4 + w) * 16;

  f32x4 acc[4];
#pragma unroll
  for (int mi = 0; mi < 4; ++mi) acc[mi] = 0.f;

#pragma unroll 2
  for (int kk = 0; kk < 16; ++kk) {
    f16x8 b = *(const f16x8*)(fint + (long)(n0 + col) * 512 + kk * 32 + kg * 8);
#pragma unroll
    for (int mi = 0; mi < 4; ++mi) {
      f16x8 a = *(const f16x8*)(ys + (m0 + mi * 16 + col) * 512 + kk * 32 + kg * 8);
      acc[mi] = __builtin_amdgcn_mfma_f32_16x16x32_f16(a, b, acc[mi], 0, 0, 0);
    }
  }
  const int n = n0 + col;
  const float bn = finb[n];
#pragma unroll
  for (int mi = 0; mi < 4; ++mi)
#pragma unroll
    for (int r = 0; r < 4; ++r)
      out[(m0 + mi * 16 + kg * 4 + r) * 512 + n] = sigmoidf_(acc[mi][r] + bn);
}

extern "C" void kernel_launch(void* const* d_in, const int* in_sizes, int n_in,
                              void* d_out, int out_size, void* d_ws, size_t ws_size,
                              hipStream_t stream) {
  const float* x      = (const float*)d_in[0];
  const float* enc_W  = (const float*)d_in[2];
  const float* enc_V  = (const float*)d_in[3];
  const float* enc_b  = (const float*)d_in[4];
  const float* enc_h0 = (const float*)d_in[5];
  const float* enc_c0 = (const float*)d_in[6];
  const float* dec_W  = (const float*)d_in[7];
  const float* dec_V  = (const float*)d_in[8];
  const float* dec_b  = (const float*)d_in[9];
  const float* dec_h0 = (const float*)d_in[10];
  const float* dec_c0 = (const float*)d_in[11];
  const float* fin_W  = (const float*)d_in[12];
  const float* fin_b  = (const float*)d_in[13];
  float* out = (float*)d_out;

  // workspace layout (offsets match Round 2; c regions retired but reserved)
  f16* wt_enc = (f16*)d_ws;                                   // 16*2048*1024
  f16* wt_dec = wt_enc + (long)16 * 2048 * 1024;              // 16*2048*1024
  f16* xt     = wt_dec + (long)16 * 2048 * 1024;              // 256*64*512
  f16* fint   = xt + (long)SL * BS * SI;                      // 512*512
  f16* ys     = fint + (long)SH * SI;                         // 64*1024*512
  f16* h_enc  = ys + (long)BS * (FL * 4) * SH;                // 2*4*64*512
  f16* h_dec  = h_enc + (long)2 * 4 * BS * SH;                // 2*4*64*512
  float* c_unused = (float*)(h_dec + (long)2 * 4 * BS * SH);  // reserved
  int* ctr = (int*)(c_unused + (long)8 * BS * SH);

  hipMemsetAsync(ctr, 0, 256, stream);

  conv_w<<<131072, 256, 0, stream>>>(enc_W, enc_V, wt_enc);
  conv_w<<<131072, 256, 0, stream>>>(dec_W, dec_V, wt_dec);
  conv_x<<<32768, 256, 0, stream>>>(x, xt);
  conv_fin<<<1024, 256, 0, stream>>>(fin_W, fint);
  init_state<<<512, 256, 0, stream>>>(enc_h0, dec_h0, h_enc, h_dec);

  lstm_persist<<<NBLK, 512, 0, stream>>>(xt, wt_enc, wt_dec, enc_b, dec_b,
                                         enc_c0, dec_c0, h_enc, h_dec, ys, ctr);

  dim3 fg(8, 1024);
  final_gemm<<<fg, 256, 0, stream>>>(ys, fint, fin_b, out);
}

// Round 5
// 147845.801 us; speedup vs baseline: 1.2761x; 1.2761x over previous
//
#include <hip/hip_runtime.h>

typedef _Float16 f16;
typedef _Float16 f16x8 __attribute__((ext_vector_type(8)));
typedef float f32x4 __attribute__((ext_vector_type(4)));

#define BS 64
#define SL 256
#define FL 256
#define SI 512
#define SH 512
#define NBLK 256
#define ESTEPS 1027

__device__ __forceinline__ float sigmoidf_(float x) { return 1.f / (1.f + __expf(-x)); }
__device__ __forceinline__ float tanhf_(float x) { float e = __expf(2.f * x); return 1.f - 2.f / (e + 1.f); }

// Weights packed in MFMA-fragment order:
// widx = (((((cell*32+nt)*4+g)*2+kh)*16+kk)*64 + lane)*8 + j
// n = g*512 + nt*16 + (lane&15), k = kh*512 + kk*32 + (lane>>4)*8 + j
__global__ void conv_w(const float* __restrict__ W, const float* __restrict__ V,
                       f16* __restrict__ out) {
  long idx = (long)blockIdx.x * blockDim.x + threadIdx.x;  // total 2^25
  int j    = (int)(idx & 7);
  int lane = (int)((idx >> 3) & 63);
  int kk   = (int)((idx >> 9) & 15);
  int kh   = (int)((idx >> 13) & 1);
  int g    = (int)((idx >> 14) & 3);
  int nt   = (int)((idx >> 16) & 31);
  long cell = idx >> 21;
  int n = g * 512 + nt * 16 + (lane & 15);
  int k = kh * 512 + kk * 32 + (lane >> 4) * 8 + j;
  float v = (k < 512) ? W[(cell * 512 + k) * 2048 + n]
                      : V[(cell * 512 + (k - 512)) * 2048 + n];
  out[idx] = (f16)v;
}

__global__ void conv_x(const float* __restrict__ x, f16* __restrict__ xt) {
  long idx = (long)blockIdx.x * blockDim.x + threadIdx.x;  // 256*64*512
  int i = (int)(idx & 511);
  int b = (int)((idx >> 9) & 63);
  int t = (int)(idx >> 15);
  xt[idx] = (f16)x[((long)b * SL + t) * SI + i];
}

__global__ void conv_fin(const float* __restrict__ finW, f16* __restrict__ fint) {
  long idx = (long)blockIdx.x * blockDim.x + threadIdx.x;  // 512*512
  int k = (int)(idx & 511);
  int n = (int)(idx >> 9);
  fint[idx] = (f16)finW[(long)k * SI + n];
}

// h_enc both parities = enc_h0 ; h_dec parity-1 slabs = dec_h0
__global__ void init_state(const float* __restrict__ h0e, const float* __restrict__ h0d,
                           f16* __restrict__ h_enc, f16* __restrict__ h_dec) {
  long idx = (long)blockIdx.x * blockDim.x + threadIdx.x;  // 4*64*512 = 131072
  f16 he = (f16)h0e[idx];
  h_enc[idx] = he;
  h_enc[idx + 131072] = he;
  h_dec[idx + 131072] = (f16)h0d[idx];
}

#define GBAR(STEPIDX) do {                                                         \
    __syncthreads();                                                               \
    if (tid == 0) {                                                                \
      __threadfence();                                                             \
      __hip_atomic_fetch_add(ctr, 1, __ATOMIC_RELEASE, __HIP_MEMORY_SCOPE_AGENT);  \
      while (__hip_atomic_load(ctr, __ATOMIC_ACQUIRE, __HIP_MEMORY_SCOPE_AGENT) <  \
             (STEPIDX) * NBLK)                                                     \
        __builtin_amdgcn_s_sleep(2);                                               \
    }                                                                              \
    __syncthreads();                                                               \
  } while (0)

// Encoder body: anti-diagonal wavefront. 64 blocks per cell: (emt 0..1) x (nt 0..31).
// Wave (g, kh): 16 cols x 32 rows x 512 k -> 32 MFMAs.
#define ENC_BODY(DD, P, BUSE, BPRE) do {                                           \
    const int v = (DD) - eslot;                                                    \
    if (v >= 0 && v < 1024) {                                                      \
      const int L = v & 3, t = v >> 2;                                             \
      const f16* inp = (eslot == 0) ? (xt + (long)t * HSz)                         \
                                    : (h_enc + ((P)*4 + (eslot - 1)) * HSz);       \
      const f16* hin = h_enc + ((P)*4 + eslot) * HSz;                              \
      f16* hout = h_enc + ((1 - (P))*4 + eslot) * HSz;                             \
      const f16* abase = ((kh == 0) ? inp : hin) + (emt*32 + col) * SH + kg * 8;   \
      f32x4 acc0 = 0.f, acc1 = 0.f;                                                \
      _Pragma("unroll")                                                            \
      for (int kk = 0; kk < 16; ++kk) {                                            \
        const f16* ab = abase + kk * 32;                                           \
        f16x8 a0 = *(const f16x8*)(ab);                                            \
        f16x8 a1 = *(const f16x8*)(ab + 16 * SH);                                  \
        acc0 = __builtin_amdgcn_mfma_f32_16x16x32_f16(a0, BUSE[kk], acc0, 0,0,0);  \
        acc1 = __builtin_amdgcn_mfma_f32_16x16x32_f16(a1, BUSE[kk], acc1, 0,0,0);  \
      }                                                                            \
      const f16* wn = (v + 1 < 1024)                                               \
          ? wt_enc + ((long)(((v + 1) & 3) * 4 + eslot) << 21) + wslice            \
          : wt_dec + wslice;                                                       \
      _Pragma("unroll")                                                            \
      for (int kk = 0; kk < 16; ++kk) BPRE[kk] = *(const f16x8*)(wn + kk * 512);   \
      _Pragma("unroll")                                                            \
      for (int r = 0; r < 4; ++r) {                                                \
        zred[wid][kg*4 + r][col] = acc0[r];                                        \
        zred[wid][16 + kg*4 + r][col] = acc1[r];                                   \
      }                                                                            \
      __syncthreads();                                                             \
      {                                                                            \
        const int row = tid >> 4, ci = tid & 15, n = n0 + ci;                      \
        const int grow = emt * 32 + row;                                           \
        const float* bias = enc_b + (L * 4 + eslot) * 2048;                        \
        float zf = bias[n]      + zred[0][row][ci] + zred[4][row][ci];             \
        float zi = bias[512+n]  + zred[1][row][ci] + zred[5][row][ci];             \
        float zg = bias[1024+n] + zred[2][row][ci] + zred[6][row][ci];             \
        float zo = bias[1536+n] + zred[3][row][ci] + zred[7][row][ci];             \
        float f_ = sigmoidf_(zf), i_ = sigmoidf_(zi);                              \
        float g_ = tanhf_(zg),   o_ = sigmoidf_(zo);                               \
        float cin = (v == 0) ? enc_c0[(long)eslot * HSz + grow * SH + n] : ce;     \
        float cc = f_ * cin + i_ * g_;                                             \
        ce = cc;                                                                   \
        hout[grow * SH + n] = (f16)(o_ * tanhf_(cc));                              \
      }                                                                            \
    }                                                                              \
  } while (0)

// Decoder body: all 256 blocks on one cell: (dmt 0..7) x (nt 0..31).
// Wave (g, kh): 16 cols x 8 rows (dup to 16) x 512 k -> 16 MFMAs.
#define DEC_BODY(E, BUSE, BPRE, CD) do {                                           \
    const f16* inp;                                                                \
    if ((E) == 0)                                                                  \
      inp = (vv == 0) ? state0 : h_dec + ((par ^ 1) * 4 + 3) * HSz;                \
    else                                                                           \
      inp = h_dec + (par * 4 + (E) - 1) * HSz;                                     \
    const f16* hin = h_dec + ((par ^ 1) * 4 + (E)) * HSz;                          \
    f16* hout = h_dec + (par * 4 + (E)) * HSz;                                     \
    const f16* abase = ((kh == 0) ? inp : hin) + (dmt*8 + (col & 7)) * SH + kg*8;  \
    f32x4 acc = 0.f;                                                               \
    _Pragma("unroll")                                                              \
    for (int kk = 0; kk < 16; ++kk) {                                              \
      f16x8 a = *(const f16x8*)(abase + kk * 32);                                  \
      acc = __builtin_amdgcn_mfma_f32_16x16x32_f16(a, BUSE[kk], acc, 0,0,0);       \
    }                                                                              \
    const f16* wn;                                                                 \
    bool dopf;                                                                     \
    if ((E) < 3) {                                                                 \
      wn = wt_dec + ((long)(L * 4 + (E) + 1) << 21) + wslice; dopf = true;         \
    } else {                                                                       \
      wn = wt_dec + ((long)(((vv + 1) & 3) * 4) << 21) + wslice;                   \
      dopf = (vv < 1023);                                                          \
    }                                                                              \
    if (dopf) {                                                                    \
      _Pragma("unroll")                                                            \
      for (int kk = 0; kk < 16; ++kk) BPRE[kk] = *(const f16x8*)(wn + kk * 512);   \
    }                                                                              \
    if (kg < 2) {                                                                  \
      _Pragma("unroll")                                                            \
      for (int r = 0; r < 4; ++r) zred[wid][kg*4 + r][col] = acc[r];               \
    }                                                                              \
    __syncthreads();                                                               \
    if (tid < 128) {                                                               \
      const int row = tid >> 4, ci = tid & 15, n = n0 + ci;                        \
      const int grow = dmt * 8 + row;                                              \
      const float* bias = dec_b + (L * 4 + (E)) * 2048;                            \
      float zf = bias[n]      + zred[0][row][ci] + zred[4][row][ci];               \
      float zi = bias[512+n]  + zred[1][row][ci] + zred[5][row][ci];               \
      float zg = bias[1024+n] + zred[2][row][ci] + zred[6][row][ci];               \
      float zo = bias[1536+n] + zred[3][row][ci] + zred[7][row][ci];               \
      float f_ = sigmoidf_(zf), i_ = sigmoidf_(zi);                                \
      float g_ = tanhf_(zg),   o_ = sigmoidf_(zo);                                 \
      float cin = (vv == 0) ? dec_c0[(long)(E) * HSz + grow * SH + n] : CD;        \
      float cc = f_ * cin + i_ * g_;                                               \
      CD = cc;                                                                     \
      f16 h = (f16)(o_ * tanhf_(cc));                                              \
      hout[grow * SH + n] = h;                                                     \
      if ((E) == 3) ys[((long)grow * 1024 + vv) * SH + n] = h;                     \
    }                                                                              \
  } while (0)

__global__ __launch_bounds__(512, 2) void lstm_persist(
    const f16* __restrict__ xt,
    const f16* __restrict__ wt_enc, const f16* __restrict__ wt_dec,
    const float* __restrict__ enc_b, const float* __restrict__ dec_b,
    const float* __restrict__ enc_c0, const float* __restrict__ dec_c0,
    f16* __restrict__ h_enc, f16* __restrict__ h_dec,
    f16* __restrict__ ys, int* __restrict__ ctr) {
  const int tid = threadIdx.x;
  const int lane = tid & 63;
  const int wid = tid >> 6;   // 0..7
  const int g = wid & 3;      // gate
  const int kh = wid >> 2;    // K-half
  const int col = lane & 15;
  const int kg = lane >> 4;
  const int idx = blockIdx.x;
  const int nt = idx & 31;        // idx%8 == nt%8 -> weight-sharing siblings co-XCD
  const int n0 = nt << 4;
  const int eslot = idx >> 6;     // encoder role: 4 groups of 64 blocks
  const int emt = (idx >> 5) & 1; // encoder M-split (32 rows)
  const int dmt = idx >> 5;       // decoder M-split (8 rows)

  __shared__ float zred[8][32][17];

  const long wslice = ((long)(nt * 4 + g) * 2 + kh) * 8192 + lane * 8;
  const int HSz = BS * SH;
  const f16* const state0 = h_enc + (1 * 4 + 3) * HSz;

  f16x8 B[16], Bn[16];
  {  // preload first encoder cell (L=0, e=eslot) into the parity-matching buffer
    const f16* w = wt_enc + ((long)eslot << 21) + wslice;
    if (eslot & 1) {
#pragma unroll
      for (int kk = 0; kk < 16; ++kk) Bn[kk] = *(const f16x8*)(w + kk * 512);
    } else {
#pragma unroll
      for (int kk = 0; kk < 16; ++kk) B[kk] = *(const f16x8*)(w + kk * 512);
    }
  }

  float ce = 0.f;
  float cd0 = 0.f, cd1 = 0.f, cd2 = 0.f, cd3 = 0.f;

  // -------- encoder: anti-diagonal wavefront, diagonals 0..1026 --------
  for (int d = 0;; d += 2) {
    ENC_BODY(d, 0, B, Bn);
    GBAR(d + 1);
    if (d == 1026) break;
    ENC_BODY(d + 1, 1, Bn, B);
    GBAR(d + 2);
  }

  // normalize: decoder cell 0 weights into B for all blocks
  if (eslot & 1) {
#pragma unroll
    for (int kk = 0; kk < 16; ++kk) B[kk] = Bn[kk];
  }

  // -------- decoder: fully serial, 4096 cells, unrolled x4 --------
  for (int vv = 0; vv < 1024; ++vv) {
    const int L = vv & 3, par = vv & 1;
    DEC_BODY(0, B, Bn, cd0);
    GBAR(ESTEPS + vv * 4 + 1);
    DEC_BODY(1, Bn, B, cd1);
    GBAR(ESTEPS + vv * 4 + 2);
    DEC_BODY(2, B, Bn, cd2);
    GBAR(ESTEPS + vv * 4 + 3);
    DEC_BODY(3, Bn, B, cd3);
    GBAR(ESTEPS + vv * 4 + 4);
  }
}

// out[m][n] = sigmoid( ys[m][:] @ fint[n][:] + fin_b[n] )
__global__ __launch_bounds__(256) void final_gemm(const f16* __restrict__ ys,
                                                  const f16* __restrict__ fint,
                                                  const float* __restrict__ finb,
                                                  float* __restrict__ out) {
  const int lane = threadIdx.x & 63;
  const int w = threadIdx.x >> 6;
  const int col = lane & 15;
  const int kg = lane >> 4;
  const long m0 = (long)blockIdx.y * 64;
  const int n0 = (blockIdx.x * 4 + w) * 16;

  f32x4 acc[4];
#pragma unroll
  for (int mi = 0; mi < 4; ++mi) acc[mi] = 0.f;

#pragma unroll 2
  for (int kk = 0; kk < 16; ++kk) {
    f16x8 b = *(const f16x8*)(fint + (long)(n0 + col) * 512 + kk * 32 + kg * 8);
#pragma unroll
    for (int mi = 0; mi < 4; ++mi) {
      f16x8 a = *(const f16x8*)(ys + (m0 + mi * 16 + col) * 512 + kk * 32 + kg * 8);
      acc[mi] = __builtin_amdgcn_mfma_f32_16x16x32_f16(a, b, acc[mi], 0, 0, 0);
    }
  }
  const int n = n0 + col;
  const float bn = finb[n];
#pragma unroll
  for (int mi = 0; mi < 4; ++mi)
#pragma unroll
    for (int r = 0; r < 4; ++r)
      out[(m0 + mi * 16 + kg * 4 + r) * 512 + n] = sigmoidf_(acc[mi][r] + bn);
}

extern "C" void kernel_launch(void* const* d_in, const int* in_sizes, int n_in,
                              void* d_out, int out_size, void* d_ws, size_t ws_size,
                              hipStream_t stream) {
  const float* x      = (const float*)d_in[0];
  const float* enc_W  = (const float*)d_in[2];
  const float* enc_V  = (const float*)d_in[3];
  const float* enc_b  = (const float*)d_in[4];
  const float* enc_h0 = (const float*)d_in[5];
  const float* enc_c0 = (const float*)d_in[6];
  const float* dec_W  = (const float*)d_in[7];
  const float* dec_V  = (const float*)d_in[8];
  const float* dec_b  = (const float*)d_in[9];
  const float* dec_h0 = (const float*)d_in[10];
  const float* dec_c0 = (const float*)d_in[11];
  const float* fin_W  = (const float*)d_in[12];
  const float* fin_b  = (const float*)d_in[13];
  float* out = (float*)d_out;

  // workspace layout
  f16* wt_enc = (f16*)d_ws;                                   // 16*2048*1024
  f16* wt_dec = wt_enc + (long)16 * 2048 * 1024;              // 16*2048*1024
  f16* xt     = wt_dec + (long)16 * 2048 * 1024;              // 256*64*512
  f16* fint   = xt + (long)SL * BS * SI;                      // 512*512
  f16* ys     = fint + (long)SH * SI;                         // 64*1024*512
  f16* h_enc  = ys + (long)BS * (FL * 4) * SH;                // 2*4*64*512
  f16* h_dec  = h_enc + (long)2 * 4 * BS * SH;                // 2*4*64*512
  float* c_unused = (float*)(h_dec + (long)2 * 4 * BS * SH);  // reserved
  int* ctr = (int*)(c_unused + (long)8 * BS * SH);

  hipMemsetAsync(ctr, 0, 256, stream);

  conv_w<<<131072, 256, 0, stream>>>(enc_W, enc_V, wt_enc);
  conv_w<<<131072, 256, 0, stream>>>(dec_W, dec_V, wt_dec);
  conv_x<<<32768, 256, 0, stream>>>(x, xt);
  conv_fin<<<1024, 256, 0, stream>>>(fin_W, fint);
  init_state<<<512, 256, 0, stream>>>(enc_h0, dec_h0, h_enc, h_dec);

  lstm_persist<<<NBLK, 512, 0, stream>>>(xt, wt_enc, wt_dec, enc_b, dec_b,
                                         enc_c0, dec_c0, h_enc, h_dec, ys, ctr);

  dim3 fg(8, 1024);
  final_gemm<<<fg, 256, 0, stream>>>(ys, fint, fin_b, out);
}

// Round 6
// 46899.023 us; speedup vs baseline: 4.0228x; 3.1524x over previous
//
#include <hip/hip_runtime.h>

typedef _Float16 f16;
typedef _Float16 f16x8 __attribute__((ext_vector_type(8)));
typedef float f32x4 __attribute__((ext_vector_type(4)));

#define BS 64
#define SL 256
#define FL 256
#define SI 512
#define SH 512
#define NBLK 256
#define ESTEPS 1027

__device__ __forceinline__ float sigmoidf_(float x) { return 1.f / (1.f + __expf(-x)); }
__device__ __forceinline__ float tanhf_(float x) { float e = __expf(2.f * x); return 1.f - 2.f / (e + 1.f); }

// Weights packed in MFMA-fragment order:
// widx = (((((cell*32+nt)*4+g)*2+kh)*16+kk)*64 + lane)*8 + j
// n = g*512 + nt*16 + (lane&15), k = kh*512 + kk*32 + (lane>>4)*8 + j
__global__ void conv_w(const float* __restrict__ W, const float* __restrict__ V,
                       f16* __restrict__ out) {
  long idx = (long)blockIdx.x * blockDim.x + threadIdx.x;  // total 2^25
  int j    = (int)(idx & 7);
  int lane = (int)((idx >> 3) & 63);
  int kk   = (int)((idx >> 9) & 15);
  int kh   = (int)((idx >> 13) & 1);
  int g    = (int)((idx >> 14) & 3);
  int nt   = (int)((idx >> 16) & 31);
  long cell = idx >> 21;
  int n = g * 512 + nt * 16 + (lane & 15);
  int k = kh * 512 + kk * 32 + (lane >> 4) * 8 + j;
  float v = (k < 512) ? W[(cell * 512 + k) * 2048 + n]
                      : V[(cell * 512 + (k - 512)) * 2048 + n];
  out[idx] = (f16)v;
}

__global__ void conv_x(const float* __restrict__ x, f16* __restrict__ xt) {
  long idx = (long)blockIdx.x * blockDim.x + threadIdx.x;  // 256*64*512
  int i = (int)(idx & 511);
  int b = (int)((idx >> 9) & 63);
  int t = (int)(idx >> 15);
  xt[idx] = (f16)x[((long)b * SL + t) * SI + i];
}

__global__ void conv_fin(const float* __restrict__ finW, f16* __restrict__ fint) {
  long idx = (long)blockIdx.x * blockDim.x + threadIdx.x;  // 512*512
  int k = (int)(idx & 511);
  int n = (int)(idx >> 9);
  fint[idx] = (f16)finW[(long)k * SI + n];
}

// h_enc both parities = enc_h0 ; h_dec parity-1 slabs = dec_h0
__global__ void init_state(const float* __restrict__ h0e, const float* __restrict__ h0d,
                           f16* __restrict__ h_enc, f16* __restrict__ h_dec) {
  long idx = (long)blockIdx.x * blockDim.x + threadIdx.x;  // 4*64*512 = 131072
  f16 he = (f16)h0e[idx];
  h_enc[idx] = he;
  h_enc[idx + 131072] = he;
  h_dec[idx + 131072] = (f16)h0d[idx];
}

__device__ __forceinline__ void store_h_agent(f16* p, float v) {
  f16 h = (f16)v;
  __hip_atomic_store((unsigned short*)p, __builtin_bit_cast(unsigned short, h),
                     __ATOMIC_RELAXED, __HIP_MEMORY_SCOPE_AGENT);
}

// Flat barrier, O(1) fabric ops per block per step:
//  - each block relaxed-stores arrival into its own padded word (no RMW)
//  - block 0's threads poll all words RELAXED (no per-poll invalidate), flip epoch
//  - other leaders spin on epoch RELAXED; ONE acquire fence (buffer_inv) at exit
#define GBAR(TARGET) do {                                                          \
    __syncthreads(); /* vmcnt(0): all sc1 h-stores complete at coherence point */  \
    if (blockIdx.x == 0) {                                                         \
      if (tid > 0 && tid < NBLK) {                                                 \
        while (__hip_atomic_load(&bar[tid * 16], __ATOMIC_RELAXED,                 \
                                 __HIP_MEMORY_SCOPE_AGENT) < (TARGET))             \
          __builtin_amdgcn_s_sleep(4);                                             \
      }                                                                            \
      __syncthreads();                                                             \
      if (tid == 0)                                                                \
        __hip_atomic_store(&bar[4096], (TARGET), __ATOMIC_RELAXED,                 \
                           __HIP_MEMORY_SCOPE_AGENT);                              \
    } else {                                                                       \
      if (tid == 0) {                                                              \
        __hip_atomic_store(&bar[(int)blockIdx.x * 16], (TARGET),                   \
                           __ATOMIC_RELAXED, __HIP_MEMORY_SCOPE_AGENT);            \
        while (__hip_atomic_load(&bar[4096], __ATOMIC_RELAXED,                     \
                                 __HIP_MEMORY_SCOPE_AGENT) < (TARGET))             \
          __builtin_amdgcn_s_sleep(8);                                             \
      }                                                                            \
    }                                                                              \
    if (tid == 0) __builtin_amdgcn_fence(__ATOMIC_ACQUIRE, "agent");               \
    __syncthreads();                                                               \
  } while (0)

// Encoder body: anti-diagonal wavefront. 64 blocks per cell: (emt 0..1) x (nt 0..31).
#define ENC_BODY(DD, P, BUSE, BPRE) do {                                           \
    const int v = (DD) - eslot;                                                    \
    if (v >= 0 && v < 1024) {                                                      \
      const int L = v & 3, t = v >> 2;                                             \
      const f16* inp = (eslot == 0) ? (xt + (long)t * HSz)                         \
                                    : (h_enc + ((P)*4 + (eslot - 1)) * HSz);       \
      const f16* hin = h_enc + ((P)*4 + eslot) * HSz;                              \
      f16* hout = h_enc + ((1 - (P))*4 + eslot) * HSz;                             \
      const f16* abase = ((kh == 0) ? inp : hin) + (emt*32 + col) * SH + kg * 8;   \
      f32x4 acc0 = 0.f, acc1 = 0.f;                                                \
      _Pragma("unroll")                                                            \
      for (int kk = 0; kk < 16; ++kk) {                                            \
        const f16* ab = abase + kk * 32;                                           \
        f16x8 a0 = *(const f16x8*)(ab);                                            \
        f16x8 a1 = *(const f16x8*)(ab + 16 * SH);                                  \
        acc0 = __builtin_amdgcn_mfma_f32_16x16x32_f16(a0, BUSE[kk], acc0, 0,0,0);  \
        acc1 = __builtin_amdgcn_mfma_f32_16x16x32_f16(a1, BUSE[kk], acc1, 0,0,0);  \
      }                                                                            \
      const f16* wn = (v + 1 < 1024)                                               \
          ? wt_enc + ((long)(((v + 1) & 3) * 4 + eslot) << 21) + wslice            \
          : wt_dec + wslice;                                                       \
      _Pragma("unroll")                                                            \
      for (int kk = 0; kk < 16; ++kk) BPRE[kk] = *(const f16x8*)(wn + kk * 512);   \
      _Pragma("unroll")                                                            \
      for (int r = 0; r < 4; ++r) {                                                \
        zred[wid][kg*4 + r][col] = acc0[r];                                        \
        zred[wid][16 + kg*4 + r][col] = acc1[r];                                   \
      }                                                                            \
      __syncthreads();                                                             \
      {                                                                            \
        const int row = tid >> 4, ci = tid & 15, n = n0 + ci;                      \
        const int grow = emt * 32 + row;                                           \
        const float* bias = enc_b + (L * 4 + eslot) * 2048;                        \
        float zf = bias[n]      + zred[0][row][ci] + zred[4][row][ci];             \
        float zi = bias[512+n]  + zred[1][row][ci] + zred[5][row][ci];             \
        float zg = bias[1024+n] + zred[2][row][ci] + zred[6][row][ci];             \
        float zo = bias[1536+n] + zred[3][row][ci] + zred[7][row][ci];             \
        float f_ = sigmoidf_(zf), i_ = sigmoidf_(zi);                              \
        float g_ = tanhf_(zg),   o_ = sigmoidf_(zo);                               \
        float cin = (v == 0) ? enc_c0[(long)eslot * HSz + grow * SH + n] : ce;     \
        float cc = f_ * cin + i_ * g_;                                             \
        ce = cc;                                                                   \
        store_h_agent(hout + grow * SH + n, o_ * tanhf_(cc));                      \
      }                                                                            \
    }                                                                              \
  } while (0)

// Decoder body: all 256 blocks on one cell: (dmt 0..7) x (nt 0..31).
#define DEC_BODY(E, BUSE, BPRE, CD) do {                                           \
    const f16* inp;                                                                \
    if ((E) == 0)                                                                  \
      inp = (vv == 0) ? state0 : h_dec + ((par ^ 1) * 4 + 3) * HSz;                \
    else                                                                           \
      inp = h_dec + (par * 4 + (E) - 1) * HSz;                                     \
    const f16* hin = h_dec + ((par ^ 1) * 4 + (E)) * HSz;                          \
    f16* hout = h_dec + (par * 4 + (E)) * HSz;                                     \
    const f16* abase = ((kh == 0) ? inp : hin) + (dmt*8 + (col & 7)) * SH + kg*8;  \
    f32x4 acc = 0.f;                                                               \
    _Pragma("unroll")                                                              \
    for (int kk = 0; kk < 16; ++kk) {                                              \
      f16x8 a = *(const f16x8*)(abase + kk * 32);                                  \
      acc = __builtin_amdgcn_mfma_f32_16x16x32_f16(a, BUSE[kk], acc, 0,0,0);       \
    }                                                                              \
    const f16* wn;                                                                 \
    bool dopf;                                                                     \
    if ((E) < 3) {                                                                 \
      wn = wt_dec + ((long)(L * 4 + (E) + 1) << 21) + wslice; dopf = true;         \
    } else {                                                                       \
      wn = wt_dec + ((long)(((vv + 1) & 3) * 4) << 21) + wslice;                   \
      dopf = (vv < 1023);                                                          \
    }                                                                              \
    if (dopf) {                                                                    \
      _Pragma("unroll")                                                            \
      for (int kk = 0; kk < 16; ++kk) BPRE[kk] = *(const f16x8*)(wn + kk * 512);   \
    }                                                                              \
    if (kg < 2) {                                                                  \
      _Pragma("unroll")                                                            \
      for (int r = 0; r < 4; ++r) zred[wid][kg*4 + r][col] = acc[r];               \
    }                                                                              \
    __syncthreads();                                                               \
    if (tid < 128) {                                                               \
      const int row = tid >> 4, ci = tid & 15, n = n0 + ci;                        \
      const int grow = dmt * 8 + row;                                              \
      const float* bias = dec_b + (L * 4 + (E)) * 2048;                            \
      float zf = bias[n]      + zred[0][row][ci] + zred[4][row][ci];               \
      float zi = bias[512+n]  + zred[1][row][ci] + zred[5][row][ci];               \
      float zg = bias[1024+n] + zred[2][row][ci] + zred[6][row][ci];               \
      float zo = bias[1536+n] + zred[3][row][ci] + zred[7][row][ci];               \
      float f_ = sigmoidf_(zf), i_ = sigmoidf_(zi);                                \
      float g_ = tanhf_(zg),   o_ = sigmoidf_(zo);                                 \
      float cin = (vv == 0) ? dec_c0[(long)(E) * HSz + grow * SH + n] : CD;        \
      float cc = f_ * cin + i_ * g_;                                               \
      CD = cc;                                                                     \
      float hv = o_ * tanhf_(cc);                                                  \
      store_h_agent(hout + grow * SH + n, hv);                                     \
      if ((E) == 3) ys[((long)grow * 1024 + vv) * SH + n] = (f16)hv;               \
    }                                                                              \
  } while (0)

__global__ __launch_bounds__(512, 2) void lstm_persist(
    const f16* __restrict__ xt,
    const f16* __restrict__ wt_enc, const f16* __restrict__ wt_dec,
    const float* __restrict__ enc_b, const float* __restrict__ dec_b,
    const float* __restrict__ enc_c0, const float* __restrict__ dec_c0,
    f16* __restrict__ h_enc, f16* __restrict__ h_dec,
    f16* __restrict__ ys, int* __restrict__ bar) {
  const int tid = threadIdx.x;
  const int lane = tid & 63;
  const int wid = tid >> 6;   // 0..7
  const int g = wid & 3;      // gate
  const int kh = wid >> 2;    // K-half
  const int col = lane & 15;
  const int kg = lane >> 4;
  const int idx = blockIdx.x;
  const int nt = idx & 31;        // idx%8 == nt%8 -> weight-sharing siblings co-XCD
  const int n0 = nt << 4;
  const int eslot = idx >> 6;     // encoder role: 4 groups of 64 blocks
  const int emt = (idx >> 5) & 1; // encoder M-split (32 rows)
  const int dmt = idx >> 5;       // decoder M-split (8 rows)

  __shared__ float zred[8][32][17];

  const long wslice = ((long)(nt * 4 + g) * 2 + kh) * 8192 + lane * 8;
  const int HSz = BS * SH;
  const f16* const state0 = h_enc + (1 * 4 + 3) * HSz;

  f16x8 B[16], Bn[16];
  {  // preload first encoder cell (L=0, e=eslot) into the parity-matching buffer
    const f16* w = wt_enc + ((long)eslot << 21) + wslice;
    if (eslot & 1) {
#pragma unroll
      for (int kk = 0; kk < 16; ++kk) Bn[kk] = *(const f16x8*)(w + kk * 512);
    } else {
#pragma unroll
      for (int kk = 0; kk < 16; ++kk) B[kk] = *(const f16x8*)(w + kk * 512);
    }
  }

  float ce = 0.f;
  float cd0 = 0.f, cd1 = 0.f, cd2 = 0.f, cd3 = 0.f;

  // -------- encoder: anti-diagonal wavefront, diagonals 0..1026 --------
  for (int d = 0;; d += 2) {
    ENC_BODY(d, 0, B, Bn);
    GBAR(d + 1);
    if (d == 1026) break;
    ENC_BODY(d + 1, 1, Bn, B);
    GBAR(d + 2);
  }

  // normalize: decoder cell 0 weights into B for all blocks
  if (eslot & 1) {
#pragma unroll
    for (int kk = 0; kk < 16; ++kk) B[kk] = Bn[kk];
  }

  // -------- decoder: fully serial, 4096 cells, unrolled x4 --------
  for (int vv = 0; vv < 1024; ++vv) {
    const int L = vv & 3, par = vv & 1;
    DEC_BODY(0, B, Bn, cd0);
    GBAR(ESTEPS + vv * 4 + 1);
    DEC_BODY(1, Bn, B, cd1);
    GBAR(ESTEPS + vv * 4 + 2);
    DEC_BODY(2, B, Bn, cd2);
    GBAR(ESTEPS + vv * 4 + 3);
    DEC_BODY(3, Bn, B, cd3);
    GBAR(ESTEPS + vv * 4 + 4);
  }
}

// out[m][n] = sigmoid( ys[m][:] @ fint[n][:] + fin_b[n] )
__global__ __launch_bounds__(256) void final_gemm(const f16* __restrict__ ys,
                                                  const f16* __restrict__ fint,
                                                  const float* __restrict__ finb,
                                                  float* __restrict__ out) {
  const int lane = threadIdx.x & 63;
  const int w = threadIdx.x >> 6;
  const int col = lane & 15;
  const int kg = lane >> 4;
  const long m0 = (long)blockIdx.y * 64;
  const int n0 = (blockIdx.x * 4 + w) * 16;

  f32x4 acc[4];
#pragma unroll
  for (int mi = 0; mi < 4; ++mi) acc[mi] = 0.f;

#pragma unroll 2
  for (int kk = 0; kk < 16; ++kk) {
    f16x8 b = *(const f16x8*)(fint + (long)(n0 + col) * 512 + kk * 32 + kg * 8);
#pragma unroll
    for (int mi = 0; mi < 4; ++mi) {
      f16x8 a = *(const f16x8*)(ys + (m0 + mi * 16 + col) * 512 + kk * 32 + kg * 8);
      acc[mi] = __builtin_amdgcn_mfma_f32_16x16x32_f16(a, b, acc[mi], 0, 0, 0);
    }
  }
  const int n = n0 + col;
  const float bn = finb[n];
#pragma unroll
  for (int mi = 0; mi < 4; ++mi)
#pragma unroll
    for (int r = 0; r < 4; ++r)
      out[(m0 + mi * 16 + kg * 4 + r) * 512 + n] = sigmoidf_(acc[mi][r] + bn);
}

extern "C" void kernel_launch(void* const* d_in, const int* in_sizes, int n_in,
                              void* d_out, int out_size, void* d_ws, size_t ws_size,
                              hipStream_t stream) {
  const float* x      = (const float*)d_in[0];
  const float* enc_W  = (const float*)d_in[2];
  const float* enc_V  = (const float*)d_in[3];
  const float* enc_b  = (const float*)d_in[4];
  const float* enc_h0 = (const float*)d_in[5];
  const float* enc_c0 = (const float*)d_in[6];
  const float* dec_W  = (const float*)d_in[7];
  const float* dec_V  = (const float*)d_in[8];
  const float* dec_b  = (const float*)d_in[9];
  const float* dec_h0 = (const float*)d_in[10];
  const float* dec_c0 = (const float*)d_in[11];
  const float* fin_W  = (const float*)d_in[12];
  const float* fin_b  = (const float*)d_in[13];
  float* out = (float*)d_out;

  // workspace layout
  f16* wt_enc = (f16*)d_ws;                                   // 16*2048*1024
  f16* wt_dec = wt_enc + (long)16 * 2048 * 1024;              // 16*2048*1024
  f16* xt     = wt_dec + (long)16 * 2048 * 1024;              // 256*64*512
  f16* fint   = xt + (long)SL * BS * SI;                      // 512*512
  f16* ys     = fint + (long)SH * SI;                         // 64*1024*512
  f16* h_enc  = ys + (long)BS * (FL * 4) * SH;                // 2*4*64*512
  f16* h_dec  = h_enc + (long)2 * 4 * BS * SH;                // 2*4*64*512
  float* c_unused = (float*)(h_dec + (long)2 * 4 * BS * SH);  // reserved
  int* bar = (int*)(c_unused + (long)8 * BS * SH);            // arrive[256*16] + epoch

  hipMemsetAsync(bar, 0, 32768, stream);

  conv_w<<<131072, 256, 0, stream>>>(enc_W, enc_V, wt_enc);
  conv_w<<<131072, 256, 0, stream>>>(dec_W, dec_V, wt_dec);
  conv_x<<<32768, 256, 0, stream>>>(x, xt);
  conv_fin<<<1024, 256, 0, stream>>>(fin_W, fint);
  init_state<<<512, 256, 0, stream>>>(enc_h0, dec_h0, h_enc, h_dec);

  lstm_persist<<<NBLK, 512, 0, stream>>>(xt, wt_enc, wt_dec, enc_b, dec_b,
                                         enc_c0, dec_c0, h_enc, h_dec, ys, bar);

  dim3 fg(8, 1024);
  final_gemm<<<fg, 256, 0, stream>>>(ys, fint, fin_b, out);
}